// Round 14
// baseline (1972.616 us; speedup 1.0000x reference)
//
#include <hip/hip_runtime.h>
#include <float.h>

#define DD 52
#define VE 151
#define NTOT 393216
#define PSZ 131072

// output offsets (floats)
#define OFF0 0                       // predicate_conf  P*52
#define OFF1 (PSZ*DD)                // entity_conf     P*151
#define OFF2 (OFF1 + PSZ*VE)         // predicate_logits P*52
#define OFF3 (OFF2 + PSZ*DD)         // entity_logits   P*151
#define OFF4 (OFF3 + PSZ*VE)         // all_labels      N (as float)

#define SORT_BLOCKS 384              // N / 1024

typedef float f32x4 __attribute__((ext_vector_type(4)));

// ---------- stable counting sort by node_type (3 buckets) ----------
__global__ __launch_bounds__(256) void count_kernel(const int* __restrict__ nt,
                                                    int* __restrict__ partial) {
  __shared__ int cnt[3];
  int tid = threadIdx.x;
  if (tid < 3) cnt[tid] = 0;
  __syncthreads();
  int base = blockIdx.x * 1024 + tid * 4;
  int4 v = *(const int4*)(nt + base);
  int t0 = min(max(v.x, 0), 2), t1 = min(max(v.y, 0), 2);
  int t2 = min(max(v.z, 0), 2), t3 = min(max(v.w, 0), 2);
  atomicAdd(&cnt[t0], 1); atomicAdd(&cnt[t1], 1);
  atomicAdd(&cnt[t2], 1); atomicAdd(&cnt[t3], 1);
  __syncthreads();
  if (tid < 3) partial[blockIdx.x * 3 + tid] = cnt[tid];
}

__global__ __launch_bounds__(384) void scan_kernel(const int* __restrict__ partial,
                                                   int* __restrict__ blockBase) {
  __shared__ int sA[3][SORT_BLOCKS];
  int b = threadIdx.x;
  int p0 = partial[b * 3 + 0], p1 = partial[b * 3 + 1], p2 = partial[b * 3 + 2];
  sA[0][b] = p0; sA[1][b] = p1; sA[2][b] = p2;
  __syncthreads();
  for (int off = 1; off < SORT_BLOCKS; off <<= 1) {
    int a0 = 0, a1 = 0, a2 = 0;
    if (b >= off) { a0 = sA[0][b - off]; a1 = sA[1][b - off]; a2 = sA[2][b - off]; }
    __syncthreads();
    sA[0][b] += a0; sA[1][b] += a1; sA[2][b] += a2;
    __syncthreads();
  }
  int tot0 = sA[0][SORT_BLOCKS - 1];
  int tot1 = sA[1][SORT_BLOCKS - 1];
  blockBase[b * 3 + 0] = sA[0][b] - p0;
  blockBase[b * 3 + 1] = tot0 + sA[1][b] - p1;
  blockBase[b * 3 + 2] = tot0 + tot1 + sA[2][b] - p2;
}

__global__ __launch_bounds__(256) void scatter_kernel(const int* __restrict__ nt,
                                                      const int* __restrict__ blockBase,
                                                      int* __restrict__ order) {
  __shared__ int s0[256], s1[256], s2[256];
  int tid = threadIdx.x;
  int gbase = blockIdx.x * 1024 + tid * 4;
  int4 v = *(const int4*)(nt + gbase);
  int t[4] = { min(max(v.x, 0), 2), min(max(v.y, 0), 2),
               min(max(v.z, 0), 2), min(max(v.w, 0), 2) };
  int c0 = 0, c1 = 0, c2 = 0;
#pragma unroll
  for (int i = 0; i < 4; ++i) { c0 += (t[i] == 0); c1 += (t[i] == 1); c2 += (t[i] == 2); }
  s0[tid] = c0; s1[tid] = c1; s2[tid] = c2;
  __syncthreads();
  for (int off = 1; off < 256; off <<= 1) {
    int a0 = 0, a1 = 0, a2 = 0;
    if (tid >= off) { a0 = s0[tid - off]; a1 = s1[tid - off]; a2 = s2[tid - off]; }
    __syncthreads();
    s0[tid] += a0; s1[tid] += a1; s2[tid] += a2;
    __syncthreads();
  }
  int o0 = blockBase[blockIdx.x * 3 + 0] + s0[tid] - c0;
  int o1 = blockBase[blockIdx.x * 3 + 1] + s1[tid] - c1;
  int o2 = blockBase[blockIdx.x * 3 + 2] + s2[tid] - c2;
#pragma unroll
  for (int i = 0; i < 4; ++i) {
    int ty = t[i]; int dest;
    if (ty == 0) dest = o0++;
    else if (ty == 1) dest = o1++;
    else dest = o2++;
    order[dest] = gbase + i;
  }
}

// ---------- fold FC into downstream weights ----------
__global__ __launch_bounds__(256) void combine_kernel(const float* __restrict__ FCw,
                                                      const float* __restrict__ FCb,
                                                      const float* __restrict__ Wpl,
                                                      const float* __restrict__ Went,
                                                      float* __restrict__ Wc,
                                                      float* __restrict__ bc,
                                                      float* __restrict__ Wpc,
                                                      float* __restrict__ bpc) {
  int idx = blockIdx.x * 256 + threadIdx.x;
  if (idx < VE * DD) {
    int v = idx / DD, k = idx % DD;
    float s = 0.f;
    for (int d = 0; d < DD; ++d) s = fmaf(Went[v * DD + d], FCw[d * DD + k], s);
    Wc[idx] = s;
  } else if (idx < VE * DD + VE) {
    int v = idx - VE * DD;
    float s = 0.f;
    for (int d = 0; d < DD; ++d) s = fmaf(FCb[d], Went[v * DD + d], s);
    bc[v] = s;
  } else if (idx < VE * DD + VE + DD * DD) {
    int t2 = idx - (VE * DD + VE);
    int j = t2 / DD, k = t2 % DD;
    float s = 0.f;
    for (int d = 0; d < DD; ++d) s = fmaf(FCw[d * DD + k], Wpl[d * DD + j], s);
    Wpc[t2] = s;
  } else if (idx < VE * DD + VE + DD * DD + DD) {
    int j = idx - (VE * DD + VE + DD * DD);
    float s = 0.f;
    for (int d = 0; d < DD; ++d) s = fmaf(FCb[d], Wpl[d * DD + j], s);
    bpc[j] = s;
  }
}

// ---------- fused main kernel ----------
// R14 = R13's 64-row ent/blank tile with the rule-#20 spill FIXED:
// every loop that indexes acc[8][5]/bvpl[8] is fully unrolled so all
// accumulator indices are compile-time (R13's `#pragma unroll 1` softmax
// and chunk loops runtime-indexed acc -> whole accumulator in scratch ->
// 3x regression, WRITE 218->470+ MB). Pred branch byte-identical to R11.
// Epilogue: 16 chunks, writer algebra 4c+(rg&3) == rg+8(c>>1) under
// (rg>>2)==(c&1) — verified.
// INVARIANTS (session-measured, do not violate):
//  - h staged via LDS (R10: direct-global = latency-bound, +75%)
//  - epilogue: both surfaces staged in LDS, clean f32x4 NT store/thread/iter
//    (R5-R8: any deviation -> 4-16x HBM write amplification)
//  - no runtime indexing of per-thread arrays (R13: scratch spill)
__global__ __launch_bounds__(256, 3) void main_kernel(const float* __restrict__ h,
                                                      const int* __restrict__ order,
                                                      const float* __restrict__ Wc,
                                                      const float* __restrict__ bc,
                                                      const float* __restrict__ Wpc,
                                                      const float* __restrict__ bpc,
                                                      float* __restrict__ out) {
  __shared__ float sW[VE * DD];   // 31408 B (pred uses 52*52)
  __shared__ float sU[3328];      // 13312 B: h-tile (832 f4) / chunk buf (1208)
  __shared__ float sb[VE + 1];
  __shared__ int   sOrd[64];
  int tid = threadIdx.x, bid = blockIdx.x;
  int rg = tid >> 5, c0 = tid & 31;

  if (bid < 512) {
    // ---------- entity / blank : 8 tiles of 64 rows ----------
    for (int i = tid; i < VE * 13; i += 256) ((float4*)sW)[i] = ((const float4*)Wc)[i];
    if (tid < VE) sb[tid] = bc[tid];
    int e = bid;

    int wbase[5];
#pragma unroll
    for (int j = 0; j < 5; ++j) {
      int col = c0 + 32 * j; if (col >= VE) col = 0;
      wbase[j] = col * 13;
    }
    int hbase[8];
#pragma unroll
    for (int r = 0; r < 8; ++r) hbase[r] = (rg + 8 * r) * 13;

#pragma unroll 1
    for (int tt = 0; tt < 8; ++tt) {
      bool isEnt = !(tt & 1);
      int idx = tt >> 1;
      int rowBase = (isEnt ? PSZ : 2 * PSZ) + e * 256 + idx * 64;

      __syncthreads();
      if (tid < 64) sOrd[tid] = order[rowBase + tid];
      __syncthreads();
      for (int i = tid; i < 64 * 13; i += 256) {
        int row = i / 13, f = i % 13;
        ((float4*)sU)[i] = ((const float4*)(h + (size_t)sOrd[row] * DD))[f];
      }
      __syncthreads();

      float acc[8][5];
#pragma unroll
      for (int r = 0; r < 8; ++r)
#pragma unroll
        for (int j = 0; j < 5; ++j) acc[r][j] = 0.f;

#pragma unroll
      for (int kc = 0; kc < 13; ++kc) {
        float4 wv[5];
#pragma unroll
        for (int j = 0; j < 5; ++j)
          wv[j] = ((const float4*)sW)[wbase[j] + kc];
#pragma unroll
        for (int r = 0; r < 8; ++r) {
          float4 hv = ((float4*)sU)[hbase[r] + kc];
#pragma unroll
          for (int j = 0; j < 5; ++j) {
            acc[r][j] = fmaf(hv.x, wv[j].x, acc[r][j]);
            acc[r][j] = fmaf(hv.y, wv[j].y, acc[r][j]);
            acc[r][j] = fmaf(hv.z, wv[j].z, acc[r][j]);
            acc[r][j] = fmaf(hv.w, wv[j].w, acc[r][j]);
          }
        }
      }

      float bvpl[8];
#pragma unroll
      for (int r = 0; r < 8; ++r) {
        float bv = -FLT_MAX; int bi = 0x7fffffff;
#pragma unroll
        for (int j = 0; j < 5; ++j) {
          int col = c0 + 32 * j;
          if (col < VE) {
            float x = acc[r][j] + sb[col];
            acc[r][j] = x;
            if (x > bv) { bv = x; bi = col; }
          }
        }
#pragma unroll
        for (int m = 16; m >= 1; m >>= 1) {
          float ov = __shfl_xor(bv, m);
          int   oi = __shfl_xor(bi, m);
          if (ov > bv || (ov == bv && oi < bi)) { bv = ov; bi = oi; }
        }
        if (isEnt) {
          float s = 0.f;
#pragma unroll
          for (int j = 0; j < 5; ++j) {
            int col = c0 + 32 * j;
            if (col < VE) s += __expf(acc[r][j] - bv);
          }
#pragma unroll
          for (int m = 16; m >= 1; m >>= 1) s += __shfl_xor(s, m);
          bvpl[r] = bv + __logf(s);
        }
        if (c0 == 0) out[OFF4 + sOrd[rg + 8 * r]] = (float)bi;
      }

      if (isEnt) {
        int q0base = rowBase - PSZ;
#pragma unroll
        for (int c = 0; c < 16; ++c) {
          __syncthreads();
          if ((rg >> 2) == (c & 1)) {
            const int r = c >> 1;          // compile-time (c-loop fully unrolled)
            int ri = rg & 3;
#pragma unroll
            for (int j = 0; j < 5; ++j) {
              int col = c0 + 32 * j;
              if (col < VE) {
                float lg = acc[r][j];
                sU[ri * VE + col] = lg - bvpl[r];
                sU[604 + ri * VE + col] = lg;
              }
            }
          }
          __syncthreads();
          int q0 = q0base + 4 * c;
          f32x4* dC = (f32x4*)(out + OFF1 + (size_t)q0 * VE);
          f32x4* dL = (f32x4*)(out + OFF3 + (size_t)q0 * VE);
          for (int i = tid; i < 302; i += 256) {
            f32x4 v = ((f32x4*)sU)[i];
            if (i < 151) __builtin_nontemporal_store(v, dC + i);
            else         __builtin_nontemporal_store(v, dL + (i - 151));
          }
        }
      }
    }
  } else {
    // ---------- predicate : 8 tiles of 32 rows (byte-identical to R11) ----------
    for (int i = tid; i < DD * 13; i += 256) ((float4*)sW)[i] = ((const float4*)Wpc)[i];
    if (tid < DD) sb[tid] = bpc[tid];
    int p = bid - 512;

    int wbase[2];
#pragma unroll
    for (int j = 0; j < 2; ++j) {
      int col = c0 + 32 * j; if (col >= DD) col = 0;
      wbase[j] = col * 13;
    }
    int hbase[4];
#pragma unroll
    for (int r = 0; r < 4; ++r) hbase[r] = (rg + 8 * r) * 13;

#pragma unroll 1
    for (int tt = 0; tt < 8; ++tt) {
      int rowBase = p * 256 + tt * 32;

      __syncthreads();
      if (tid < 32) sOrd[tid] = order[rowBase + tid];
      __syncthreads();
      for (int i = tid; i < 32 * 13; i += 256) {
        int row = i / 13, f = i % 13;
        ((float4*)sU)[i] = ((const float4*)(h + (size_t)sOrd[row] * DD))[f];
      }
      __syncthreads();

      float acc[4][2];
#pragma unroll
      for (int r = 0; r < 4; ++r) { acc[r][0] = 0.f; acc[r][1] = 0.f; }

#pragma unroll
      for (int kc = 0; kc < 13; ++kc) {
        float4 wv[2];
#pragma unroll
        for (int j = 0; j < 2; ++j)
          wv[j] = ((const float4*)sW)[wbase[j] + kc];
#pragma unroll
        for (int r = 0; r < 4; ++r) {
          float4 hv = ((float4*)sU)[hbase[r] + kc];
#pragma unroll
          for (int j = 0; j < 2; ++j) {
            acc[r][j] = fmaf(hv.x, wv[j].x, acc[r][j]);
            acc[r][j] = fmaf(hv.y, wv[j].y, acc[r][j]);
            acc[r][j] = fmaf(hv.z, wv[j].z, acc[r][j]);
            acc[r][j] = fmaf(hv.w, wv[j].w, acc[r][j]);
          }
        }
      }

      float bvpl[4];
#pragma unroll 1
      for (int r = 0; r < 4; ++r) {
        float bv = -FLT_MAX; int bi = 0x7fffffff;
#pragma unroll
        for (int j = 0; j < 2; ++j) {
          int col = c0 + 32 * j;
          if (col < DD) {
            float x = acc[r][j] + sb[col];
            acc[r][j] = x;
            if (x > bv) { bv = x; bi = col; }
          }
        }
#pragma unroll
        for (int m = 16; m >= 1; m >>= 1) {
          float ov = __shfl_xor(bv, m);
          int   oi = __shfl_xor(bi, m);
          if (ov > bv || (ov == bv && oi < bi)) { bv = ov; bi = oi; }
        }
        float s = 0.f;
#pragma unroll
        for (int j = 0; j < 2; ++j) {
          int col = c0 + 32 * j;
          if (col < DD) s += __expf(acc[r][j] - bv);
        }
#pragma unroll
        for (int m = 16; m >= 1; m >>= 1) s += __shfl_xor(s, m);
        bvpl[r] = bv + __logf(s);
        if (c0 == 0) out[OFF4 + sOrd[rg + 8 * r]] = (float)bi;
      }

#pragma unroll 1
      for (int c = 0; c < 8; ++c) {
        __syncthreads();
        if ((rg >> 2) == (c & 1)) {
          int r = c >> 1, ri = rg & 3;
#pragma unroll
          for (int j = 0; j < 2; ++j) {
            int col = c0 + 32 * j;
            if (col < DD) {
              float lg = acc[r][j];
              sU[ri * DD + col] = lg - bvpl[r];
              sU[208 + ri * DD + col] = lg;
            }
          }
        }
        __syncthreads();
        int q0 = rowBase + 4 * c;
        f32x4* dC = (f32x4*)(out + OFF0 + (size_t)q0 * DD);
        f32x4* dL = (f32x4*)(out + OFF2 + (size_t)q0 * DD);
        for (int i = tid; i < 104; i += 256) {
          f32x4 v = ((f32x4*)sU)[i];
          if (i < 52) __builtin_nontemporal_store(v, dC + i);
          else        __builtin_nontemporal_store(v, dL + (i - 52));
        }
      }
    }
  }
}

extern "C" void kernel_launch(void* const* d_in, const int* in_sizes, int n_in,
                              void* d_out, int out_size, void* d_ws, size_t ws_size,
                              hipStream_t stream) {
  const float* h    = (const float*)d_in[0];
  const int*   nt   = (const int*)d_in[1];
  const float* FCw  = (const float*)d_in[2];
  const float* FCb  = (const float*)d_in[3];
  const float* Wpl  = (const float*)d_in[4];
  const float* Went = (const float*)d_in[5];
  float* out = (float*)d_out;

  int* order     = (int*)d_ws;                 // N
  int* partial   = order + NTOT;               // 384*3
  int* blockBase = partial + SORT_BLOCKS * 3;  // 384*3
  float* Wc  = (float*)(blockBase + SORT_BLOCKS * 3);  // 151*52 (16B-aligned)
  float* bc  = Wc + VE * DD;                   // 151 (+1 pad)
  float* Wpc = bc + VE + 1;                    // 52*52
  float* bpc = Wpc + DD * DD;                  // 52

  combine_kernel<<<43, 256, 0, stream>>>(FCw, FCb, Wpl, Went, Wc, bc, Wpc, bpc);
  count_kernel  <<<SORT_BLOCKS, 256, 0, stream>>>(nt, partial);
  scan_kernel   <<<1, SORT_BLOCKS, 0, stream>>>(partial, blockBase);
  scatter_kernel<<<SORT_BLOCKS, 256, 0, stream>>>(nt, blockBase, order);
  main_kernel   <<<1024, 256, 0, stream>>>(h, order, Wc, bc, Wpc, bpc, out);
}

// Round 15
// 184.693 us; speedup vs baseline: 10.6805x; 10.6805x over previous
//
#include <hip/hip_runtime.h>
#include <float.h>

#define DD 52
#define VE 151
#define NTOT 393216
#define PSZ 131072

// output offsets (floats)
#define OFF0 0                       // predicate_conf  P*52
#define OFF1 (PSZ*DD)                // entity_conf     P*151
#define OFF2 (OFF1 + PSZ*VE)         // predicate_logits P*52
#define OFF3 (OFF2 + PSZ*DD)         // entity_logits   P*151
#define OFF4 (OFF3 + PSZ*VE)         // all_labels      N (as float)

#define SORT_BLOCKS 384              // N / 1024
#define TMR 32                       // rows per tile

typedef float f32x4 __attribute__((ext_vector_type(4)));

// ---------- count (blocks 0..383) + weight-fold (blocks 384..426) ----------
// Fused: the two are fully independent (count reads nt -> partial; combine
// reads FC/W -> ws weights). Saves one kernel launch of serial gap.
__global__ __launch_bounds__(256) void count_combine_kernel(const int* __restrict__ nt,
                                                            int* __restrict__ partial,
                                                            const float* __restrict__ FCw,
                                                            const float* __restrict__ FCb,
                                                            const float* __restrict__ Wpl,
                                                            const float* __restrict__ Went,
                                                            float* __restrict__ Wc,
                                                            float* __restrict__ bc,
                                                            float* __restrict__ Wpc,
                                                            float* __restrict__ bpc) {
  int tid = threadIdx.x;
  if (blockIdx.x < SORT_BLOCKS) {
    __shared__ int cnt[3];
    if (tid < 3) cnt[tid] = 0;
    __syncthreads();
    int base = blockIdx.x * 1024 + tid * 4;
    int4 v = *(const int4*)(nt + base);
    int t0 = min(max(v.x, 0), 2), t1 = min(max(v.y, 0), 2);
    int t2 = min(max(v.z, 0), 2), t3 = min(max(v.w, 0), 2);
    atomicAdd(&cnt[t0], 1); atomicAdd(&cnt[t1], 1);
    atomicAdd(&cnt[t2], 1); atomicAdd(&cnt[t3], 1);
    __syncthreads();
    if (tid < 3) partial[blockIdx.x * 3 + tid] = cnt[tid];
  } else {
    int idx = (blockIdx.x - SORT_BLOCKS) * 256 + tid;
    if (idx < VE * DD) {
      int v = idx / DD, k = idx % DD;
      float s = 0.f;
      for (int d = 0; d < DD; ++d) s = fmaf(Went[v * DD + d], FCw[d * DD + k], s);
      Wc[idx] = s;
    } else if (idx < VE * DD + VE) {
      int v = idx - VE * DD;
      float s = 0.f;
      for (int d = 0; d < DD; ++d) s = fmaf(FCb[d], Went[v * DD + d], s);
      bc[v] = s;
    } else if (idx < VE * DD + VE + DD * DD) {
      int t2 = idx - (VE * DD + VE);
      int j = t2 / DD, k = t2 % DD;
      float s = 0.f;
      for (int d = 0; d < DD; ++d) s = fmaf(FCw[d * DD + k], Wpl[d * DD + j], s);
      Wpc[t2] = s;
    } else if (idx < VE * DD + VE + DD * DD + DD) {
      int j = idx - (VE * DD + VE + DD * DD);
      float s = 0.f;
      for (int d = 0; d < DD; ++d) s = fmaf(FCb[d], Wpl[d * DD + j], s);
      bpc[j] = s;
    }
  }
}

__global__ __launch_bounds__(384) void scan_kernel(const int* __restrict__ partial,
                                                   int* __restrict__ blockBase) {
  __shared__ int sA[3][SORT_BLOCKS];
  int b = threadIdx.x;
  int p0 = partial[b * 3 + 0], p1 = partial[b * 3 + 1], p2 = partial[b * 3 + 2];
  sA[0][b] = p0; sA[1][b] = p1; sA[2][b] = p2;
  __syncthreads();
  for (int off = 1; off < SORT_BLOCKS; off <<= 1) {
    int a0 = 0, a1 = 0, a2 = 0;
    if (b >= off) { a0 = sA[0][b - off]; a1 = sA[1][b - off]; a2 = sA[2][b - off]; }
    __syncthreads();
    sA[0][b] += a0; sA[1][b] += a1; sA[2][b] += a2;
    __syncthreads();
  }
  int tot0 = sA[0][SORT_BLOCKS - 1];
  int tot1 = sA[1][SORT_BLOCKS - 1];
  blockBase[b * 3 + 0] = sA[0][b] - p0;
  blockBase[b * 3 + 1] = tot0 + sA[1][b] - p1;
  blockBase[b * 3 + 2] = tot0 + tot1 + sA[2][b] - p2;
}

__global__ __launch_bounds__(256) void scatter_kernel(const int* __restrict__ nt,
                                                      const int* __restrict__ blockBase,
                                                      int* __restrict__ order) {
  __shared__ int s0[256], s1[256], s2[256];
  int tid = threadIdx.x;
  int gbase = blockIdx.x * 1024 + tid * 4;
  int4 v = *(const int4*)(nt + gbase);
  int t[4] = { min(max(v.x, 0), 2), min(max(v.y, 0), 2),
               min(max(v.z, 0), 2), min(max(v.w, 0), 2) };
  int c0 = 0, c1 = 0, c2 = 0;
#pragma unroll
  for (int i = 0; i < 4; ++i) { c0 += (t[i] == 0); c1 += (t[i] == 1); c2 += (t[i] == 2); }
  s0[tid] = c0; s1[tid] = c1; s2[tid] = c2;
  __syncthreads();
  for (int off = 1; off < 256; off <<= 1) {
    int a0 = 0, a1 = 0, a2 = 0;
    if (tid >= off) { a0 = s0[tid - off]; a1 = s1[tid - off]; a2 = s2[tid - off]; }
    __syncthreads();
    s0[tid] += a0; s1[tid] += a1; s2[tid] += a2;
    __syncthreads();
  }
  int o0 = blockBase[blockIdx.x * 3 + 0] + s0[tid] - c0;
  int o1 = blockBase[blockIdx.x * 3 + 1] + s1[tid] - c1;
  int o2 = blockBase[blockIdx.x * 3 + 2] + s2[tid] - c2;
#pragma unroll
  for (int i = 0; i < 4; ++i) {
    int ty = t[i]; int dest;
    if (ty == 0) dest = o0++;
    else if (ty == 1) dest = o1++;
    else dest = o2++;
    order[dest] = gbase + i;
  }
}

// ---------- fused main kernel (byte-exact R11 — measured-good) ----------
// grid = 1024. bid<512: ent/blank block e=bid: 16 tiles of 32 rows,
//   interleaved ent (P + e*256 + i*32) / blank (2P + e*256 + i*32).
// bid>=512: pred block p=bid-512: 8 tiles of 32 rows from p*256.
// INVARIANTS (session-measured, do not violate):
//  - h staged via LDS (R10: direct-global = latency-bound, +75%)
//  - epilogue: both surfaces staged in LDS (4-row chunks, #pragma unroll 1
//    chunk loop), one clean f32x4 NT store/thread/iter
//    (R5-R8: any deviation -> 4-16x HBM write amplification)
//  - 32-row tiles, acc[4][5] (R13/R14: 64-row acc[8][5] -> scratch, 3-10x)
//  - no runtime indexing of per-thread arrays
__global__ __launch_bounds__(256, 4) void main_kernel(const float* __restrict__ h,
                                                      const int* __restrict__ order,
                                                      const float* __restrict__ Wc,
                                                      const float* __restrict__ bc,
                                                      const float* __restrict__ Wpc,
                                                      const float* __restrict__ bpc,
                                                      float* __restrict__ out) {
  __shared__ float sW[VE * DD];   // 31408 B (pred uses 52*52)
  __shared__ float sU[1664];      // 6656 B: h-tile (416 f4) / chunk buf
  __shared__ float sb[VE + 1];
  __shared__ int   sOrd[TMR];
  int tid = threadIdx.x, bid = blockIdx.x;
  int rg = tid >> 5, c0 = tid & 31;

  if (bid < 512) {
    // ---------- entity / blank ----------
    for (int i = tid; i < VE * 13; i += 256) ((float4*)sW)[i] = ((const float4*)Wc)[i];
    if (tid < VE) sb[tid] = bc[tid];
    int e = bid;

    int wbase[5];
#pragma unroll
    for (int j = 0; j < 5; ++j) {
      int col = c0 + 32 * j; if (col >= VE) col = 0;
      wbase[j] = col * 13;
    }
    int hbase[4];
#pragma unroll
    for (int r = 0; r < 4; ++r) hbase[r] = (rg + 8 * r) * 13;

#pragma unroll 1
    for (int tt = 0; tt < 16; ++tt) {
      bool isEnt = !(tt & 1);
      int idx = tt >> 1;
      int rowBase = (isEnt ? PSZ : 2 * PSZ) + e * 256 + idx * 32;

      __syncthreads();
      if (tid < TMR) sOrd[tid] = order[rowBase + tid];
      __syncthreads();
      for (int i = tid; i < TMR * 13; i += 256) {
        int row = i / 13, f = i % 13;
        ((float4*)sU)[i] = ((const float4*)(h + (size_t)sOrd[row] * DD))[f];
      }
      __syncthreads();

      float acc[4][5];
#pragma unroll
      for (int r = 0; r < 4; ++r)
#pragma unroll
        for (int j = 0; j < 5; ++j) acc[r][j] = 0.f;

#pragma unroll
      for (int kc = 0; kc < 13; ++kc) {
        float4 wv[5];
#pragma unroll
        for (int j = 0; j < 5; ++j)
          wv[j] = ((const float4*)sW)[wbase[j] + kc];
#pragma unroll
        for (int r = 0; r < 4; ++r) {
          float4 hv = ((float4*)sU)[hbase[r] + kc];
#pragma unroll
          for (int j = 0; j < 5; ++j) {
            acc[r][j] = fmaf(hv.x, wv[j].x, acc[r][j]);
            acc[r][j] = fmaf(hv.y, wv[j].y, acc[r][j]);
            acc[r][j] = fmaf(hv.z, wv[j].z, acc[r][j]);
            acc[r][j] = fmaf(hv.w, wv[j].w, acc[r][j]);
          }
        }
      }

      float bvpl[4];
#pragma unroll 1
      for (int r = 0; r < 4; ++r) {
        float bv = -FLT_MAX; int bi = 0x7fffffff;
#pragma unroll
        for (int j = 0; j < 5; ++j) {
          int col = c0 + 32 * j;
          if (col < VE) {
            float x = acc[r][j] + sb[col];
            acc[r][j] = x;
            if (x > bv) { bv = x; bi = col; }
          }
        }
#pragma unroll
        for (int m = 16; m >= 1; m >>= 1) {
          float ov = __shfl_xor(bv, m);
          int   oi = __shfl_xor(bi, m);
          if (ov > bv || (ov == bv && oi < bi)) { bv = ov; bi = oi; }
        }
        if (isEnt) {
          float s = 0.f;
#pragma unroll
          for (int j = 0; j < 5; ++j) {
            int col = c0 + 32 * j;
            if (col < VE) s += __expf(acc[r][j] - bv);
          }
#pragma unroll
          for (int m = 16; m >= 1; m >>= 1) s += __shfl_xor(s, m);
          bvpl[r] = bv + __logf(s);
        }
        if (c0 == 0) out[OFF4 + sOrd[rg + 8 * r]] = (float)bi;
      }

      if (isEnt) {
        int q0base = rowBase - PSZ;
#pragma unroll 1
        for (int c = 0; c < 8; ++c) {
          __syncthreads();
          if ((rg >> 2) == (c & 1)) {
            int r = c >> 1, ri = rg & 3;
#pragma unroll
            for (int j = 0; j < 5; ++j) {
              int col = c0 + 32 * j;
              if (col < VE) {
                float lg = acc[r][j];
                sU[ri * VE + col] = lg - bvpl[r];
                sU[604 + ri * VE + col] = lg;
              }
            }
          }
          __syncthreads();
          int q0 = q0base + 4 * c;
          f32x4* dC = (f32x4*)(out + OFF1 + (size_t)q0 * VE);
          f32x4* dL = (f32x4*)(out + OFF3 + (size_t)q0 * VE);
          for (int i = tid; i < 302; i += 256) {
            f32x4 v = ((f32x4*)sU)[i];
            if (i < 151) __builtin_nontemporal_store(v, dC + i);
            else         __builtin_nontemporal_store(v, dL + (i - 151));
          }
        }
      }
    }
  } else {
    // ---------- predicate ----------
    for (int i = tid; i < DD * 13; i += 256) ((float4*)sW)[i] = ((const float4*)Wpc)[i];
    if (tid < DD) sb[tid] = bpc[tid];
    int p = bid - 512;

    int wbase[2];
#pragma unroll
    for (int j = 0; j < 2; ++j) {
      int col = c0 + 32 * j; if (col >= DD) col = 0;
      wbase[j] = col * 13;
    }
    int hbase[4];
#pragma unroll
    for (int r = 0; r < 4; ++r) hbase[r] = (rg + 8 * r) * 13;

#pragma unroll 1
    for (int tt = 0; tt < 8; ++tt) {
      int rowBase = p * 256 + tt * 32;

      __syncthreads();
      if (tid < TMR) sOrd[tid] = order[rowBase + tid];
      __syncthreads();
      for (int i = tid; i < TMR * 13; i += 256) {
        int row = i / 13, f = i % 13;
        ((float4*)sU)[i] = ((const float4*)(h + (size_t)sOrd[row] * DD))[f];
      }
      __syncthreads();

      float acc[4][2];
#pragma unroll
      for (int r = 0; r < 4; ++r) { acc[r][0] = 0.f; acc[r][1] = 0.f; }

#pragma unroll
      for (int kc = 0; kc < 13; ++kc) {
        float4 wv[2];
#pragma unroll
        for (int j = 0; j < 2; ++j)
          wv[j] = ((const float4*)sW)[wbase[j] + kc];
#pragma unroll
        for (int r = 0; r < 4; ++r) {
          float4 hv = ((float4*)sU)[hbase[r] + kc];
#pragma unroll
          for (int j = 0; j < 2; ++j) {
            acc[r][j] = fmaf(hv.x, wv[j].x, acc[r][j]);
            acc[r][j] = fmaf(hv.y, wv[j].y, acc[r][j]);
            acc[r][j] = fmaf(hv.z, wv[j].z, acc[r][j]);
            acc[r][j] = fmaf(hv.w, wv[j].w, acc[r][j]);
          }
        }
      }

      float bvpl[4];
#pragma unroll 1
      for (int r = 0; r < 4; ++r) {
        float bv = -FLT_MAX; int bi = 0x7fffffff;
#pragma unroll
        for (int j = 0; j < 2; ++j) {
          int col = c0 + 32 * j;
          if (col < DD) {
            float x = acc[r][j] + sb[col];
            acc[r][j] = x;
            if (x > bv) { bv = x; bi = col; }
          }
        }
#pragma unroll
        for (int m = 16; m >= 1; m >>= 1) {
          float ov = __shfl_xor(bv, m);
          int   oi = __shfl_xor(bi, m);
          if (ov > bv || (ov == bv && oi < bi)) { bv = ov; bi = oi; }
        }
        float s = 0.f;
#pragma unroll
        for (int j = 0; j < 2; ++j) {
          int col = c0 + 32 * j;
          if (col < DD) s += __expf(acc[r][j] - bv);
        }
#pragma unroll
        for (int m = 16; m >= 1; m >>= 1) s += __shfl_xor(s, m);
        bvpl[r] = bv + __logf(s);
        if (c0 == 0) out[OFF4 + sOrd[rg + 8 * r]] = (float)bi;
      }

#pragma unroll 1
      for (int c = 0; c < 8; ++c) {
        __syncthreads();
        if ((rg >> 2) == (c & 1)) {
          int r = c >> 1, ri = rg & 3;
#pragma unroll
          for (int j = 0; j < 2; ++j) {
            int col = c0 + 32 * j;
            if (col < DD) {
              float lg = acc[r][j];
              sU[ri * DD + col] = lg - bvpl[r];
              sU[208 + ri * DD + col] = lg;
            }
          }
        }
        __syncthreads();
        int q0 = rowBase + 4 * c;
        f32x4* dC = (f32x4*)(out + OFF0 + (size_t)q0 * DD);
        f32x4* dL = (f32x4*)(out + OFF2 + (size_t)q0 * DD);
        for (int i = tid; i < 104; i += 256) {
          f32x4 v = ((f32x4*)sU)[i];
          if (i < 52) __builtin_nontemporal_store(v, dC + i);
          else        __builtin_nontemporal_store(v, dL + (i - 52));
        }
      }
    }
  }
}

extern "C" void kernel_launch(void* const* d_in, const int* in_sizes, int n_in,
                              void* d_out, int out_size, void* d_ws, size_t ws_size,
                              hipStream_t stream) {
  const float* h    = (const float*)d_in[0];
  const int*   nt   = (const int*)d_in[1];
  const float* FCw  = (const float*)d_in[2];
  const float* FCb  = (const float*)d_in[3];
  const float* Wpl  = (const float*)d_in[4];
  const float* Went = (const float*)d_in[5];
  float* out = (float*)d_out;

  int* order     = (int*)d_ws;                 // N
  int* partial   = order + NTOT;               // 384*3
  int* blockBase = partial + SORT_BLOCKS * 3;  // 384*3
  float* Wc  = (float*)(blockBase + SORT_BLOCKS * 3);  // 151*52 (16B-aligned)
  float* bc  = Wc + VE * DD;                   // 151 (+1 pad)
  float* Wpc = bc + VE + 1;                    // 52*52
  float* bpc = Wpc + DD * DD;                  // 52

  count_combine_kernel<<<SORT_BLOCKS + 43, 256, 0, stream>>>(nt, partial,
                                                             FCw, FCb, Wpl, Went,
                                                             Wc, bc, Wpc, bpc);
  scan_kernel   <<<1, SORT_BLOCKS, 0, stream>>>(partial, blockBase);
  scatter_kernel<<<SORT_BLOCKS, 256, 0, stream>>>(nt, blockBase, order);
  main_kernel   <<<1024, 256, 0, stream>>>(h, order, Wc, bc, Wpc, bpc, out);
}

// Round 16
// 180.517 us; speedup vs baseline: 10.9276x; 1.0231x over previous
//
#include <hip/hip_runtime.h>
#include <float.h>

#define DD 52
#define VE 151
#define NTOT 393216
#define PSZ 131072

// output offsets (floats)
#define OFF0 0                       // predicate_conf  P*52
#define OFF1 (PSZ*DD)                // entity_conf     P*151
#define OFF2 (OFF1 + PSZ*VE)         // predicate_logits P*52
#define OFF3 (OFF2 + PSZ*DD)         // entity_logits   P*151
#define OFF4 (OFF3 + PSZ*VE)         // all_labels      N (as float)

#define SORT_BLOCKS 384              // N / 1024
#define TMR 32                       // rows per tile

typedef float f32x4 __attribute__((ext_vector_type(4)));

// ---------- count (blocks 0..383) + weight-fold (blocks 384..426) ----------
__global__ __launch_bounds__(256) void count_combine_kernel(const int* __restrict__ nt,
                                                            int* __restrict__ partial,
                                                            const float* __restrict__ FCw,
                                                            const float* __restrict__ FCb,
                                                            const float* __restrict__ Wpl,
                                                            const float* __restrict__ Went,
                                                            float* __restrict__ Wc,
                                                            float* __restrict__ bc,
                                                            float* __restrict__ Wpc,
                                                            float* __restrict__ bpc) {
  int tid = threadIdx.x;
  if (blockIdx.x < SORT_BLOCKS) {
    __shared__ int cnt[3];
    if (tid < 3) cnt[tid] = 0;
    __syncthreads();
    int base = blockIdx.x * 1024 + tid * 4;
    int4 v = *(const int4*)(nt + base);
    int t0 = min(max(v.x, 0), 2), t1 = min(max(v.y, 0), 2);
    int t2 = min(max(v.z, 0), 2), t3 = min(max(v.w, 0), 2);
    atomicAdd(&cnt[t0], 1); atomicAdd(&cnt[t1], 1);
    atomicAdd(&cnt[t2], 1); atomicAdd(&cnt[t3], 1);
    __syncthreads();
    if (tid < 3) partial[blockIdx.x * 3 + tid] = cnt[tid];
  } else {
    int idx = (blockIdx.x - SORT_BLOCKS) * 256 + tid;
    if (idx < VE * DD) {
      int v = idx / DD, k = idx % DD;
      float s = 0.f;
      for (int d = 0; d < DD; ++d) s = fmaf(Went[v * DD + d], FCw[d * DD + k], s);
      Wc[idx] = s;
    } else if (idx < VE * DD + VE) {
      int v = idx - VE * DD;
      float s = 0.f;
      for (int d = 0; d < DD; ++d) s = fmaf(FCb[d], Went[v * DD + d], s);
      bc[v] = s;
    } else if (idx < VE * DD + VE + DD * DD) {
      int t2 = idx - (VE * DD + VE);
      int j = t2 / DD, k = t2 % DD;
      float s = 0.f;
      for (int d = 0; d < DD; ++d) s = fmaf(FCw[d * DD + k], Wpl[d * DD + j], s);
      Wpc[t2] = s;
    } else if (idx < VE * DD + VE + DD * DD + DD) {
      int j = idx - (VE * DD + VE + DD * DD);
      float s = 0.f;
      for (int d = 0; d < DD; ++d) s = fmaf(FCb[d], Wpl[d * DD + j], s);
      bpc[j] = s;
    }
  }
}

__global__ __launch_bounds__(384) void scan_kernel(const int* __restrict__ partial,
                                                   int* __restrict__ blockBase) {
  __shared__ int sA[3][SORT_BLOCKS];
  int b = threadIdx.x;
  int p0 = partial[b * 3 + 0], p1 = partial[b * 3 + 1], p2 = partial[b * 3 + 2];
  sA[0][b] = p0; sA[1][b] = p1; sA[2][b] = p2;
  __syncthreads();
  for (int off = 1; off < SORT_BLOCKS; off <<= 1) {
    int a0 = 0, a1 = 0, a2 = 0;
    if (b >= off) { a0 = sA[0][b - off]; a1 = sA[1][b - off]; a2 = sA[2][b - off]; }
    __syncthreads();
    sA[0][b] += a0; sA[1][b] += a1; sA[2][b] += a2;
    __syncthreads();
  }
  int tot0 = sA[0][SORT_BLOCKS - 1];
  int tot1 = sA[1][SORT_BLOCKS - 1];
  blockBase[b * 3 + 0] = sA[0][b] - p0;
  blockBase[b * 3 + 1] = tot0 + sA[1][b] - p1;
  blockBase[b * 3 + 2] = tot0 + tot1 + sA[2][b] - p2;
}

__global__ __launch_bounds__(256) void scatter_kernel(const int* __restrict__ nt,
                                                      const int* __restrict__ blockBase,
                                                      int* __restrict__ order) {
  __shared__ int s0[256], s1[256], s2[256];
  int tid = threadIdx.x;
  int gbase = blockIdx.x * 1024 + tid * 4;
  int4 v = *(const int4*)(nt + gbase);
  int t[4] = { min(max(v.x, 0), 2), min(max(v.y, 0), 2),
               min(max(v.z, 0), 2), min(max(v.w, 0), 2) };
  int c0 = 0, c1 = 0, c2 = 0;
#pragma unroll
  for (int i = 0; i < 4; ++i) { c0 += (t[i] == 0); c1 += (t[i] == 1); c2 += (t[i] == 2); }
  s0[tid] = c0; s1[tid] = c1; s2[tid] = c2;
  __syncthreads();
  for (int off = 1; off < 256; off <<= 1) {
    int a0 = 0, a1 = 0, a2 = 0;
    if (tid >= off) { a0 = s0[tid - off]; a1 = s1[tid - off]; a2 = s2[tid - off]; }
    __syncthreads();
    s0[tid] += a0; s1[tid] += a1; s2[tid] += a2;
    __syncthreads();
  }
  int o0 = blockBase[blockIdx.x * 3 + 0] + s0[tid] - c0;
  int o1 = blockBase[blockIdx.x * 3 + 1] + s1[tid] - c1;
  int o2 = blockBase[blockIdx.x * 3 + 2] + s2[tid] - c2;
#pragma unroll
  for (int i = 0; i < 4; ++i) {
    int ty = t[i]; int dest;
    if (ty == 0) dest = o0++;
    else if (ty == 1) dest = o1++;
    else dest = o2++;
    order[dest] = gbase + i;
  }
}

// ---------- fused main kernel ----------
// Base = R15 (byte-exact R11 main). R16 change, epilogue only: 8-row chunks.
// Chunk c covers tile rows {rg + 8c} -> EVERY warp writes its own row with
// acc[c] (runtime index into acc[4][5] — the exact pattern the working
// binary already uses). Epilogue barriers halve: 16 -> 8 per tile.
// Store loop keeps the sacred shape: clean f32x4-from-LDS NT store, one
// stream per thread per iteration. sU grows to 2416 floats -> 3 blocks/CU
// (R12 measured: residency-neutral).
// INVARIANTS (session-measured, do not violate):
//  - h staged via LDS (R10: direct-global = latency-bound, +75%)
//  - epilogue: both surfaces staged in LDS, clean f32x4 NT store/thread/iter
//    (R5-R8: any deviation -> 4-16x HBM write amplification)
//  - 32-row tiles, acc[4][5] (R13/R14: acc[8][5] -> scratch, 3-10x)
__global__ __launch_bounds__(256, 3) void main_kernel(const float* __restrict__ h,
                                                      const int* __restrict__ order,
                                                      const float* __restrict__ Wc,
                                                      const float* __restrict__ bc,
                                                      const float* __restrict__ Wpc,
                                                      const float* __restrict__ bpc,
                                                      float* __restrict__ out) {
  __shared__ float sW[VE * DD];   // 31408 B (pred uses 52*52)
  __shared__ float sU[2416];      // 9664 B: h-tile (416 f4) / chunk buf (604 f4)
  __shared__ float sb[VE + 1];
  __shared__ int   sOrd[TMR];
  int tid = threadIdx.x, bid = blockIdx.x;
  int rg = tid >> 5, c0 = tid & 31;

  if (bid < 512) {
    // ---------- entity / blank ----------
    for (int i = tid; i < VE * 13; i += 256) ((float4*)sW)[i] = ((const float4*)Wc)[i];
    if (tid < VE) sb[tid] = bc[tid];
    int e = bid;

    int wbase[5];
#pragma unroll
    for (int j = 0; j < 5; ++j) {
      int col = c0 + 32 * j; if (col >= VE) col = 0;
      wbase[j] = col * 13;
    }
    int hbase[4];
#pragma unroll
    for (int r = 0; r < 4; ++r) hbase[r] = (rg + 8 * r) * 13;

#pragma unroll 1
    for (int tt = 0; tt < 16; ++tt) {
      bool isEnt = !(tt & 1);
      int idx = tt >> 1;
      int rowBase = (isEnt ? PSZ : 2 * PSZ) + e * 256 + idx * 32;

      __syncthreads();
      if (tid < TMR) sOrd[tid] = order[rowBase + tid];
      __syncthreads();
      for (int i = tid; i < TMR * 13; i += 256) {
        int row = i / 13, f = i % 13;
        ((float4*)sU)[i] = ((const float4*)(h + (size_t)sOrd[row] * DD))[f];
      }
      __syncthreads();

      float acc[4][5];
#pragma unroll
      for (int r = 0; r < 4; ++r)
#pragma unroll
        for (int j = 0; j < 5; ++j) acc[r][j] = 0.f;

#pragma unroll
      for (int kc = 0; kc < 13; ++kc) {
        float4 wv[5];
#pragma unroll
        for (int j = 0; j < 5; ++j)
          wv[j] = ((const float4*)sW)[wbase[j] + kc];
#pragma unroll
        for (int r = 0; r < 4; ++r) {
          float4 hv = ((float4*)sU)[hbase[r] + kc];
#pragma unroll
          for (int j = 0; j < 5; ++j) {
            acc[r][j] = fmaf(hv.x, wv[j].x, acc[r][j]);
            acc[r][j] = fmaf(hv.y, wv[j].y, acc[r][j]);
            acc[r][j] = fmaf(hv.z, wv[j].z, acc[r][j]);
            acc[r][j] = fmaf(hv.w, wv[j].w, acc[r][j]);
          }
        }
      }

      float bvpl[4];
#pragma unroll 1
      for (int r = 0; r < 4; ++r) {
        float bv = -FLT_MAX; int bi = 0x7fffffff;
#pragma unroll
        for (int j = 0; j < 5; ++j) {
          int col = c0 + 32 * j;
          if (col < VE) {
            float x = acc[r][j] + sb[col];
            acc[r][j] = x;
            if (x > bv) { bv = x; bi = col; }
          }
        }
#pragma unroll
        for (int m = 16; m >= 1; m >>= 1) {
          float ov = __shfl_xor(bv, m);
          int   oi = __shfl_xor(bi, m);
          if (ov > bv || (ov == bv && oi < bi)) { bv = ov; bi = oi; }
        }
        if (isEnt) {
          float s = 0.f;
#pragma unroll
          for (int j = 0; j < 5; ++j) {
            int col = c0 + 32 * j;
            if (col < VE) s += __expf(acc[r][j] - bv);
          }
#pragma unroll
          for (int m = 16; m >= 1; m >>= 1) s += __shfl_xor(s, m);
          bvpl[r] = bv + __logf(s);
        }
        if (c0 == 0) out[OFF4 + sOrd[rg + 8 * r]] = (float)bi;
      }

      if (isEnt) {
        int q0base = rowBase - PSZ;
#pragma unroll 1
        for (int c = 0; c < 4; ++c) {
          __syncthreads();
#pragma unroll
          for (int j = 0; j < 5; ++j) {
            int col = c0 + 32 * j;
            if (col < VE) {
              float lg = acc[c][j];
              sU[rg * VE + col] = lg - bvpl[c];
              sU[1208 + rg * VE + col] = lg;
            }
          }
          __syncthreads();
          int q0 = q0base + 8 * c;
          f32x4* dC = (f32x4*)(out + OFF1 + (size_t)q0 * VE);
          f32x4* dL = (f32x4*)(out + OFF3 + (size_t)q0 * VE);
          for (int i = tid; i < 604; i += 256) {
            f32x4 v = ((f32x4*)sU)[i];
            if (i < 302) __builtin_nontemporal_store(v, dC + i);
            else         __builtin_nontemporal_store(v, dL + (i - 302));
          }
        }
      }
    }
  } else {
    // ---------- predicate ----------
    for (int i = tid; i < DD * 13; i += 256) ((float4*)sW)[i] = ((const float4*)Wpc)[i];
    if (tid < DD) sb[tid] = bpc[tid];
    int p = bid - 512;

    int wbase[2];
#pragma unroll
    for (int j = 0; j < 2; ++j) {
      int col = c0 + 32 * j; if (col >= DD) col = 0;
      wbase[j] = col * 13;
    }
    int hbase[4];
#pragma unroll
    for (int r = 0; r < 4; ++r) hbase[r] = (rg + 8 * r) * 13;

#pragma unroll 1
    for (int tt = 0; tt < 8; ++tt) {
      int rowBase = p * 256 + tt * 32;

      __syncthreads();
      if (tid < TMR) sOrd[tid] = order[rowBase + tid];
      __syncthreads();
      for (int i = tid; i < TMR * 13; i += 256) {
        int row = i / 13, f = i % 13;
        ((float4*)sU)[i] = ((const float4*)(h + (size_t)sOrd[row] * DD))[f];
      }
      __syncthreads();

      float acc[4][2];
#pragma unroll
      for (int r = 0; r < 4; ++r) { acc[r][0] = 0.f; acc[r][1] = 0.f; }

#pragma unroll
      for (int kc = 0; kc < 13; ++kc) {
        float4 wv[2];
#pragma unroll
        for (int j = 0; j < 2; ++j)
          wv[j] = ((const float4*)sW)[wbase[j] + kc];
#pragma unroll
        for (int r = 0; r < 4; ++r) {
          float4 hv = ((float4*)sU)[hbase[r] + kc];
#pragma unroll
          for (int j = 0; j < 2; ++j) {
            acc[r][j] = fmaf(hv.x, wv[j].x, acc[r][j]);
            acc[r][j] = fmaf(hv.y, wv[j].y, acc[r][j]);
            acc[r][j] = fmaf(hv.z, wv[j].z, acc[r][j]);
            acc[r][j] = fmaf(hv.w, wv[j].w, acc[r][j]);
          }
        }
      }

      float bvpl[4];
#pragma unroll 1
      for (int r = 0; r < 4; ++r) {
        float bv = -FLT_MAX; int bi = 0x7fffffff;
#pragma unroll
        for (int j = 0; j < 2; ++j) {
          int col = c0 + 32 * j;
          if (col < DD) {
            float x = acc[r][j] + sb[col];
            acc[r][j] = x;
            if (x > bv) { bv = x; bi = col; }
          }
        }
#pragma unroll
        for (int m = 16; m >= 1; m >>= 1) {
          float ov = __shfl_xor(bv, m);
          int   oi = __shfl_xor(bi, m);
          if (ov > bv || (ov == bv && oi < bi)) { bv = ov; bi = oi; }
        }
        float s = 0.f;
#pragma unroll
        for (int j = 0; j < 2; ++j) {
          int col = c0 + 32 * j;
          if (col < DD) s += __expf(acc[r][j] - bv);
        }
#pragma unroll
        for (int m = 16; m >= 1; m >>= 1) s += __shfl_xor(s, m);
        bvpl[r] = bv + __logf(s);
        if (c0 == 0) out[OFF4 + sOrd[rg + 8 * r]] = (float)bi;
      }

#pragma unroll 1
      for (int c = 0; c < 4; ++c) {
        __syncthreads();
#pragma unroll
        for (int j = 0; j < 2; ++j) {
          int col = c0 + 32 * j;
          if (col < DD) {
            float lg = acc[c][j];
            sU[rg * DD + col] = lg - bvpl[c];
            sU[416 + rg * DD + col] = lg;
          }
        }
        __syncthreads();
        int q0 = rowBase + 8 * c;
        f32x4* dC = (f32x4*)(out + OFF0 + (size_t)q0 * DD);
        f32x4* dL = (f32x4*)(out + OFF2 + (size_t)q0 * DD);
        for (int i = tid; i < 208; i += 256) {
          f32x4 v = ((f32x4*)sU)[i];
          if (i < 104) __builtin_nontemporal_store(v, dC + i);
          else         __builtin_nontemporal_store(v, dL + (i - 104));
        }
      }
    }
  }
}

extern "C" void kernel_launch(void* const* d_in, const int* in_sizes, int n_in,
                              void* d_out, int out_size, void* d_ws, size_t ws_size,
                              hipStream_t stream) {
  const float* h    = (const float*)d_in[0];
  const int*   nt   = (const int*)d_in[1];
  const float* FCw  = (const float*)d_in[2];
  const float* FCb  = (const float*)d_in[3];
  const float* Wpl  = (const float*)d_in[4];
  const float* Went = (const float*)d_in[5];
  float* out = (float*)d_out;

  int* order     = (int*)d_ws;                 // N
  int* partial   = order + NTOT;               // 384*3
  int* blockBase = partial + SORT_BLOCKS * 3;  // 384*3
  float* Wc  = (float*)(blockBase + SORT_BLOCKS * 3);  // 151*52 (16B-aligned)
  float* bc  = Wc + VE * DD;                   // 151 (+1 pad)
  float* Wpc = bc + VE + 1;                    // 52*52
  float* bpc = Wpc + DD * DD;                  // 52

  count_combine_kernel<<<SORT_BLOCKS + 43, 256, 0, stream>>>(nt, partial,
                                                             FCw, FCb, Wpl, Went,
                                                             Wc, bc, Wpc, bpc);
  scan_kernel   <<<1, SORT_BLOCKS, 0, stream>>>(partial, blockBase);
  scatter_kernel<<<SORT_BLOCKS, 256, 0, stream>>>(nt, blockBase, order);
  main_kernel   <<<1024, 256, 0, stream>>>(h, order, Wc, bc, Wpc, bpc, out);
}

// Round 17
// 179.812 us; speedup vs baseline: 10.9704x; 1.0039x over previous
//
#include <hip/hip_runtime.h>
#include <float.h>

#define DD 52
#define VE 151
#define NTOT 393216
#define PSZ 131072

// output offsets (floats)
#define OFF0 0                       // predicate_conf  P*52
#define OFF1 (PSZ*DD)                // entity_conf     P*151
#define OFF2 (OFF1 + PSZ*VE)         // predicate_logits P*52
#define OFF3 (OFF2 + PSZ*DD)         // entity_logits   P*151
#define OFF4 (OFF3 + PSZ*VE)         // all_labels      N (as float)

#define SORT_BLOCKS 384              // N / 1024
#define TMR 32                       // rows per tile

typedef float f32x4 __attribute__((ext_vector_type(4)));

// ---------- count (blocks 0..383) + weight-fold (blocks 384..426) ----------
__global__ __launch_bounds__(256) void count_combine_kernel(const int* __restrict__ nt,
                                                            int* __restrict__ partial,
                                                            const float* __restrict__ FCw,
                                                            const float* __restrict__ FCb,
                                                            const float* __restrict__ Wpl,
                                                            const float* __restrict__ Went,
                                                            float* __restrict__ Wc,
                                                            float* __restrict__ bc,
                                                            float* __restrict__ Wpc,
                                                            float* __restrict__ bpc) {
  int tid = threadIdx.x;
  if (blockIdx.x < SORT_BLOCKS) {
    __shared__ int cnt[3];
    if (tid < 3) cnt[tid] = 0;
    __syncthreads();
    int base = blockIdx.x * 1024 + tid * 4;
    int4 v = *(const int4*)(nt + base);
    int t0 = min(max(v.x, 0), 2), t1 = min(max(v.y, 0), 2);
    int t2 = min(max(v.z, 0), 2), t3 = min(max(v.w, 0), 2);
    atomicAdd(&cnt[t0], 1); atomicAdd(&cnt[t1], 1);
    atomicAdd(&cnt[t2], 1); atomicAdd(&cnt[t3], 1);
    __syncthreads();
    if (tid < 3) partial[blockIdx.x * 3 + tid] = cnt[tid];
  } else {
    int idx = (blockIdx.x - SORT_BLOCKS) * 256 + tid;
    if (idx < VE * DD) {
      int v = idx / DD, k = idx % DD;
      float s = 0.f;
      for (int d = 0; d < DD; ++d) s = fmaf(Went[v * DD + d], FCw[d * DD + k], s);
      Wc[idx] = s;
    } else if (idx < VE * DD + VE) {
      int v = idx - VE * DD;
      float s = 0.f;
      for (int d = 0; d < DD; ++d) s = fmaf(FCb[d], Went[v * DD + d], s);
      bc[v] = s;
    } else if (idx < VE * DD + VE + DD * DD) {
      int t2 = idx - (VE * DD + VE);
      int j = t2 / DD, k = t2 % DD;
      float s = 0.f;
      for (int d = 0; d < DD; ++d) s = fmaf(FCw[d * DD + k], Wpl[d * DD + j], s);
      Wpc[t2] = s;
    } else if (idx < VE * DD + VE + DD * DD + DD) {
      int j = idx - (VE * DD + VE + DD * DD);
      float s = 0.f;
      for (int d = 0; d < DD; ++d) s = fmaf(FCb[d], Wpl[d * DD + j], s);
      bpc[j] = s;
    }
  }
}

__global__ __launch_bounds__(384) void scan_kernel(const int* __restrict__ partial,
                                                   int* __restrict__ blockBase) {
  __shared__ int sA[3][SORT_BLOCKS];
  int b = threadIdx.x;
  int p0 = partial[b * 3 + 0], p1 = partial[b * 3 + 1], p2 = partial[b * 3 + 2];
  sA[0][b] = p0; sA[1][b] = p1; sA[2][b] = p2;
  __syncthreads();
  for (int off = 1; off < SORT_BLOCKS; off <<= 1) {
    int a0 = 0, a1 = 0, a2 = 0;
    if (b >= off) { a0 = sA[0][b - off]; a1 = sA[1][b - off]; a2 = sA[2][b - off]; }
    __syncthreads();
    sA[0][b] += a0; sA[1][b] += a1; sA[2][b] += a2;
    __syncthreads();
  }
  int tot0 = sA[0][SORT_BLOCKS - 1];
  int tot1 = sA[1][SORT_BLOCKS - 1];
  blockBase[b * 3 + 0] = sA[0][b] - p0;
  blockBase[b * 3 + 1] = tot0 + sA[1][b] - p1;
  blockBase[b * 3 + 2] = tot0 + tot1 + sA[2][b] - p2;
}

__global__ __launch_bounds__(256) void scatter_kernel(const int* __restrict__ nt,
                                                      const int* __restrict__ blockBase,
                                                      int* __restrict__ order) {
  __shared__ int s0[256], s1[256], s2[256];
  int tid = threadIdx.x;
  int gbase = blockIdx.x * 1024 + tid * 4;
  int4 v = *(const int4*)(nt + gbase);
  int t[4] = { min(max(v.x, 0), 2), min(max(v.y, 0), 2),
               min(max(v.z, 0), 2), min(max(v.w, 0), 2) };
  int c0 = 0, c1 = 0, c2 = 0;
#pragma unroll
  for (int i = 0; i < 4; ++i) { c0 += (t[i] == 0); c1 += (t[i] == 1); c2 += (t[i] == 2); }
  s0[tid] = c0; s1[tid] = c1; s2[tid] = c2;
  __syncthreads();
  for (int off = 1; off < 256; off <<= 1) {
    int a0 = 0, a1 = 0, a2 = 0;
    if (tid >= off) { a0 = s0[tid - off]; a1 = s1[tid - off]; a2 = s2[tid - off]; }
    __syncthreads();
    s0[tid] += a0; s1[tid] += a1; s2[tid] += a2;
    __syncthreads();
  }
  int o0 = blockBase[blockIdx.x * 3 + 0] + s0[tid] - c0;
  int o1 = blockBase[blockIdx.x * 3 + 1] + s1[tid] - c1;
  int o2 = blockBase[blockIdx.x * 3 + 2] + s2[tid] - c2;
#pragma unroll
  for (int i = 0; i < 4; ++i) {
    int ty = t[i]; int dest;
    if (ty == 0) dest = o0++;
    else if (ty == 1) dest = o1++;
    else dest = o2++;
    order[dest] = gbase + i;
  }
}

// ---------- fused main kernel ----------
// R17: grid 1024 -> 768 (= 256 CUs x 3 blocks/CU at 41.9 KB LDS) to kill
// the second-generation tail (R16: 768 resident + 256 gen-2 on 1/4 of CUs).
// bid<512: ent/blank block (UNCHANGED from R16). bid in [512,768): pred
// block p=bid-512 does 16 tiles, rowBase = p*512 + tt*32 (same tile body).
// INVARIANTS (session-measured, do not violate):
//  - h staged via LDS (R10: direct-global = latency-bound, +75%)
//  - epilogue: both surfaces staged in LDS, clean f32x4 NT store/thread/iter
//    (R5-R8: any deviation -> 4-16x HBM write amplification)
//  - 32-row tiles, acc[4][5] (R13/R14: acc[8][5] -> scratch, 3-10x)
//  - no runtime indexing of per-thread arrays beyond acc[c] patterns already
//    proven in the shipped binary
__global__ __launch_bounds__(256, 3) void main_kernel(const float* __restrict__ h,
                                                      const int* __restrict__ order,
                                                      const float* __restrict__ Wc,
                                                      const float* __restrict__ bc,
                                                      const float* __restrict__ Wpc,
                                                      const float* __restrict__ bpc,
                                                      float* __restrict__ out) {
  __shared__ float sW[VE * DD];   // 31408 B (pred uses 52*52)
  __shared__ float sU[2416];      // 9664 B: h-tile (416 f4) / chunk buf (604 f4)
  __shared__ float sb[VE + 1];
  __shared__ int   sOrd[TMR];
  int tid = threadIdx.x, bid = blockIdx.x;
  int rg = tid >> 5, c0 = tid & 31;

  if (bid < 512) {
    // ---------- entity / blank ----------
    for (int i = tid; i < VE * 13; i += 256) ((float4*)sW)[i] = ((const float4*)Wc)[i];
    if (tid < VE) sb[tid] = bc[tid];
    int e = bid;

    int wbase[5];
#pragma unroll
    for (int j = 0; j < 5; ++j) {
      int col = c0 + 32 * j; if (col >= VE) col = 0;
      wbase[j] = col * 13;
    }
    int hbase[4];
#pragma unroll
    for (int r = 0; r < 4; ++r) hbase[r] = (rg + 8 * r) * 13;

#pragma unroll 1
    for (int tt = 0; tt < 16; ++tt) {
      bool isEnt = !(tt & 1);
      int idx = tt >> 1;
      int rowBase = (isEnt ? PSZ : 2 * PSZ) + e * 256 + idx * 32;

      __syncthreads();
      if (tid < TMR) sOrd[tid] = order[rowBase + tid];
      __syncthreads();
      for (int i = tid; i < TMR * 13; i += 256) {
        int row = i / 13, f = i % 13;
        ((float4*)sU)[i] = ((const float4*)(h + (size_t)sOrd[row] * DD))[f];
      }
      __syncthreads();

      float acc[4][5];
#pragma unroll
      for (int r = 0; r < 4; ++r)
#pragma unroll
        for (int j = 0; j < 5; ++j) acc[r][j] = 0.f;

#pragma unroll
      for (int kc = 0; kc < 13; ++kc) {
        float4 wv[5];
#pragma unroll
        for (int j = 0; j < 5; ++j)
          wv[j] = ((const float4*)sW)[wbase[j] + kc];
#pragma unroll
        for (int r = 0; r < 4; ++r) {
          float4 hv = ((float4*)sU)[hbase[r] + kc];
#pragma unroll
          for (int j = 0; j < 5; ++j) {
            acc[r][j] = fmaf(hv.x, wv[j].x, acc[r][j]);
            acc[r][j] = fmaf(hv.y, wv[j].y, acc[r][j]);
            acc[r][j] = fmaf(hv.z, wv[j].z, acc[r][j]);
            acc[r][j] = fmaf(hv.w, wv[j].w, acc[r][j]);
          }
        }
      }

      float bvpl[4];
#pragma unroll 1
      for (int r = 0; r < 4; ++r) {
        float bv = -FLT_MAX; int bi = 0x7fffffff;
#pragma unroll
        for (int j = 0; j < 5; ++j) {
          int col = c0 + 32 * j;
          if (col < VE) {
            float x = acc[r][j] + sb[col];
            acc[r][j] = x;
            if (x > bv) { bv = x; bi = col; }
          }
        }
#pragma unroll
        for (int m = 16; m >= 1; m >>= 1) {
          float ov = __shfl_xor(bv, m);
          int   oi = __shfl_xor(bi, m);
          if (ov > bv || (ov == bv && oi < bi)) { bv = ov; bi = oi; }
        }
        if (isEnt) {
          float s = 0.f;
#pragma unroll
          for (int j = 0; j < 5; ++j) {
            int col = c0 + 32 * j;
            if (col < VE) s += __expf(acc[r][j] - bv);
          }
#pragma unroll
          for (int m = 16; m >= 1; m >>= 1) s += __shfl_xor(s, m);
          bvpl[r] = bv + __logf(s);
        }
        if (c0 == 0) out[OFF4 + sOrd[rg + 8 * r]] = (float)bi;
      }

      if (isEnt) {
        int q0base = rowBase - PSZ;
#pragma unroll 1
        for (int c = 0; c < 4; ++c) {
          __syncthreads();
#pragma unroll
          for (int j = 0; j < 5; ++j) {
            int col = c0 + 32 * j;
            if (col < VE) {
              float lg = acc[c][j];
              sU[rg * VE + col] = lg - bvpl[c];
              sU[1208 + rg * VE + col] = lg;
            }
          }
          __syncthreads();
          int q0 = q0base + 8 * c;
          f32x4* dC = (f32x4*)(out + OFF1 + (size_t)q0 * VE);
          f32x4* dL = (f32x4*)(out + OFF3 + (size_t)q0 * VE);
          for (int i = tid; i < 604; i += 256) {
            f32x4 v = ((f32x4*)sU)[i];
            if (i < 302) __builtin_nontemporal_store(v, dC + i);
            else         __builtin_nontemporal_store(v, dL + (i - 302));
          }
        }
      }
    }
  } else {
    // ---------- predicate : 256 blocks x 16 tiles ----------
    for (int i = tid; i < DD * 13; i += 256) ((float4*)sW)[i] = ((const float4*)Wpc)[i];
    if (tid < DD) sb[tid] = bpc[tid];
    int p = bid - 512;

    int wbase[2];
#pragma unroll
    for (int j = 0; j < 2; ++j) {
      int col = c0 + 32 * j; if (col >= DD) col = 0;
      wbase[j] = col * 13;
    }
    int hbase[4];
#pragma unroll
    for (int r = 0; r < 4; ++r) hbase[r] = (rg + 8 * r) * 13;

#pragma unroll 1
    for (int tt = 0; tt < 16; ++tt) {
      int rowBase = p * 512 + tt * 32;

      __syncthreads();
      if (tid < TMR) sOrd[tid] = order[rowBase + tid];
      __syncthreads();
      for (int i = tid; i < TMR * 13; i += 256) {
        int row = i / 13, f = i % 13;
        ((float4*)sU)[i] = ((const float4*)(h + (size_t)sOrd[row] * DD))[f];
      }
      __syncthreads();

      float acc[4][2];
#pragma unroll
      for (int r = 0; r < 4; ++r) { acc[r][0] = 0.f; acc[r][1] = 0.f; }

#pragma unroll
      for (int kc = 0; kc < 13; ++kc) {
        float4 wv[2];
#pragma unroll
        for (int j = 0; j < 2; ++j)
          wv[j] = ((const float4*)sW)[wbase[j] + kc];
#pragma unroll
        for (int r = 0; r < 4; ++r) {
          float4 hv = ((float4*)sU)[hbase[r] + kc];
#pragma unroll
          for (int j = 0; j < 2; ++j) {
            acc[r][j] = fmaf(hv.x, wv[j].x, acc[r][j]);
            acc[r][j] = fmaf(hv.y, wv[j].y, acc[r][j]);
            acc[r][j] = fmaf(hv.z, wv[j].z, acc[r][j]);
            acc[r][j] = fmaf(hv.w, wv[j].w, acc[r][j]);
          }
        }
      }

      float bvpl[4];
#pragma unroll 1
      for (int r = 0; r < 4; ++r) {
        float bv = -FLT_MAX; int bi = 0x7fffffff;
#pragma unroll
        for (int j = 0; j < 2; ++j) {
          int col = c0 + 32 * j;
          if (col < DD) {
            float x = acc[r][j] + sb[col];
            acc[r][j] = x;
            if (x > bv) { bv = x; bi = col; }
          }
        }
#pragma unroll
        for (int m = 16; m >= 1; m >>= 1) {
          float ov = __shfl_xor(bv, m);
          int   oi = __shfl_xor(bi, m);
          if (ov > bv || (ov == bv && oi < bi)) { bv = ov; bi = oi; }
        }
        float s = 0.f;
#pragma unroll
        for (int j = 0; j < 2; ++j) {
          int col = c0 + 32 * j;
          if (col < DD) s += __expf(acc[r][j] - bv);
        }
#pragma unroll
        for (int m = 16; m >= 1; m >>= 1) s += __shfl_xor(s, m);
        bvpl[r] = bv + __logf(s);
        if (c0 == 0) out[OFF4 + sOrd[rg + 8 * r]] = (float)bi;
      }

#pragma unroll 1
      for (int c = 0; c < 4; ++c) {
        __syncthreads();
#pragma unroll
        for (int j = 0; j < 2; ++j) {
          int col = c0 + 32 * j;
          if (col < DD) {
            float lg = acc[c][j];
            sU[rg * DD + col] = lg - bvpl[c];
            sU[416 + rg * DD + col] = lg;
          }
        }
        __syncthreads();
        int q0 = rowBase + 8 * c;
        f32x4* dC = (f32x4*)(out + OFF0 + (size_t)q0 * DD);
        f32x4* dL = (f32x4*)(out + OFF2 + (size_t)q0 * DD);
        for (int i = tid; i < 208; i += 256) {
          f32x4 v = ((f32x4*)sU)[i];
          if (i < 104) __builtin_nontemporal_store(v, dC + i);
          else         __builtin_nontemporal_store(v, dL + (i - 104));
        }
      }
    }
  }
}

extern "C" void kernel_launch(void* const* d_in, const int* in_sizes, int n_in,
                              void* d_out, int out_size, void* d_ws, size_t ws_size,
                              hipStream_t stream) {
  const float* h    = (const float*)d_in[0];
  const int*   nt   = (const int*)d_in[1];
  const float* FCw  = (const float*)d_in[2];
  const float* FCb  = (const float*)d_in[3];
  const float* Wpl  = (const float*)d_in[4];
  const float* Went = (const float*)d_in[5];
  float* out = (float*)d_out;

  int* order     = (int*)d_ws;                 // N
  int* partial   = order + NTOT;               // 384*3
  int* blockBase = partial + SORT_BLOCKS * 3;  // 384*3
  float* Wc  = (float*)(blockBase + SORT_BLOCKS * 3);  // 151*52 (16B-aligned)
  float* bc  = Wc + VE * DD;                   // 151 (+1 pad)
  float* Wpc = bc + VE + 1;                    // 52*52
  float* bpc = Wpc + DD * DD;                  // 52

  count_combine_kernel<<<SORT_BLOCKS + 43, 256, 0, stream>>>(nt, partial,
                                                             FCw, FCb, Wpl, Went,
                                                             Wc, bc, Wpc, bpc);
  scan_kernel   <<<1, SORT_BLOCKS, 0, stream>>>(partial, blockBase);
  scatter_kernel<<<SORT_BLOCKS, 256, 0, stream>>>(nt, blockBase, order);
  main_kernel   <<<768, 256, 0, stream>>>(h, order, Wc, bc, Wpc, bpc, out);
}